// Round 6
// baseline (1301.016 us; speedup 1.0000x reference)
//
#include <hip/hip_runtime.h>

#define N_NODES 100000
#define N_EDGES 1600000
#define D 64
#define NC 391                 // coarse buckets: col>>8 (256 nodes each)
#define NCP 392                // padded stride for count/offset matrices
#define CBLK 128               // count/scatter sub-blocks (256B write runs)
#define CEPB 12500             // edges per count/scatter sub-block
#define PBLK 448               // fused-pre grid (co-residency cap is 512)
#define PTHR 512
#define DEPB 3572              // deg edges per block (448*3572 >= E, guarded)
#define CAPC 5120              // sort LDS record capacity (mean 4092, max ~4400)
#define SCAP 768               // gather LDS stage chunk (records)
#define AST 68                 // padded LDS row stride in floats

// ---------------- software grid barrier (device-scope) ----------------
__device__ __forceinline__ void gridbar(int* bar, int nblk) {
    __threadfence();                       // release: my stores -> device scope
    __syncthreads();
    if (threadIdx.x == 0) {
        int gen = __hip_atomic_load(bar + 1, __ATOMIC_RELAXED, __HIP_MEMORY_SCOPE_AGENT);
        int prev = __hip_atomic_fetch_add(bar, 1, __ATOMIC_ACQ_REL, __HIP_MEMORY_SCOPE_AGENT);
        if (prev == nblk - 1) {
            __hip_atomic_store(bar, 0, __ATOMIC_RELAXED, __HIP_MEMORY_SCOPE_AGENT);
            __hip_atomic_fetch_add(bar + 1, 1, __ATOMIC_RELEASE, __HIP_MEMORY_SCOPE_AGENT);
        } else {
            while (__hip_atomic_load(bar + 1, __ATOMIC_ACQUIRE, __HIP_MEMORY_SCOPE_AGENT) == gen)
                __builtin_amdgcn_s_sleep(8);
        }
    }
    __syncthreads();
    __threadfence();                       // acquire: drop stale cached lines
}

__device__ __forceinline__ unsigned bf16rne(float f) {
    unsigned u = __float_as_uint(f);
    return (u + 0x7FFFu + ((u >> 16) & 1u)) >> 16;
}

// ---------------- K0: ALL preprocessing in one dispatch ----------------
__global__ __launch_bounds__(512, 4) void fused_pre(
        const float* __restrict__ x, const int* __restrict__ row,
        const int* __restrict__ col, const float* __restrict__ w,
        ushort* __restrict__ xh, float* __restrict__ deg,
        int* __restrict__ cntC, int* __restrict__ btot, int* __restrict__ cbase,
        float* __restrict__ dinv, int2* __restrict__ recA,
        int* __restrict__ node_start, int* __restrict__ bar) {
    __shared__ __align__(16) char smem[43072];   // 3 blocks/CU by LDS
    int tid = threadIdx.x;
    int b   = blockIdx.x;
    int gid = b * PTHR + tid;
    const int NT = PBLK * PTHR;

    // ---- Phase A: x -> bf16 xh; zero deg and btot ----
    for (int i = gid; i < N_NODES * D / 8; i += NT) {
        int ii = i * 8;
        float4 a  = *(const float4*)(x + ii);
        float4 b4 = *(const float4*)(x + ii + 4);
        uint4 o;
        o.x = bf16rne(a.x)  | (bf16rne(a.y)  << 16);
        o.y = bf16rne(a.z)  | (bf16rne(a.w)  << 16);
        o.z = bf16rne(b4.x) | (bf16rne(b4.y) << 16);
        o.w = bf16rne(b4.z) | (bf16rne(b4.w) << 16);
        *(uint4*)(xh + ii) = o;
    }
    for (int i = gid; i < N_NODES; i += NT) deg[i] = 0.f;
    if (gid < NC) btot[gid] = 0;
    gridbar(bar, PBLK);

    // ---- Phase B: deg atomics (all blocks) + coarse col histogram (128) ----
    {
        int base = b * DEPB;
        for (int i = tid; i < DEPB; i += PTHR) {
            int e = base + i;
            if (e < N_EDGES) atomicAdd(&deg[row[e]], w[e]);
        }
    }
    if (b < CBLK) {
        int* h = (int*)smem;
        for (int j = tid; j < NCP; j += PTHR) h[j] = 0;
        __syncthreads();
        int base = b * CEPB;
        for (int i = tid; i < CEPB; i += PTHR) atomicAdd(&h[col[base + i] >> 8], 1);
        __syncthreads();
        int* mc = cntC + (size_t)b * NCP;
        for (int j = tid; j < NC; j += PTHR) {
            int v = h[j];
            mc[j] = v;
            if (v) atomicAdd(&btot[j], v);
        }
    }
    gridbar(bar, PBLK);

    // ---- Phase CD: dinv; redundant cbase scan (per block); offset scans ----
    for (int i = gid; i < N_NODES; i += NT) {
        float dd = deg[i];
        dinv[i] = dd > 0.f ? rsqrtf(dd) : 0.f;
    }
    {
        int* sc = (int*)smem;
        int v = (tid < NC) ? btot[tid] : 0;
        sc[tid] = v;
        __syncthreads();
        for (int off = 1; off < 512; off <<= 1) {
            int u = (tid >= off) ? sc[tid - off] : 0;
            __syncthreads();
            sc[tid] += u;
            __syncthreads();
        }
        if (b == 0) {                       // global cbase for E2/gather
            if (tid < NC) cbase[tid] = sc[tid] - v;
            if (tid == 0) cbase[NC] = N_EDGES;
        }
        // per-bucket exclusive scan over the 128 sub-block counts: 1 wave/bucket
        int wv = tid >> 6, lane = tid & 63;
        for (int j = b * 8 + wv; j < NC; j += PBLK * 8) {
            int cbj = sc[j] - btot[j];      // exclusive bucket base
            int t0 = lane * 2;
            int v0 = cntC[(size_t)t0 * NCP + j];
            int v1 = cntC[(size_t)(t0 + 1) * NCP + j];
            int s = v0 + v1;
            int inc = s;
            #pragma unroll
            for (int d2 = 1; d2 < 64; d2 <<= 1) {
                int u = __shfl_up(inc, d2, 64);
                if (lane >= d2) inc += u;
            }
            int excl = cbj + inc - s;
            cntC[(size_t)t0 * NCP + j] = excl;
            cntC[(size_t)(t0 + 1) * NCP + j] = excl + v0;
        }
    }
    gridbar(bar, PBLK);

    // ---- Phase E1: deterministic coarse scatter (256B runs per block) ----
    if (b < CBLK) {
        int* curs = (int*)smem;
        const int* mc = cntC + (size_t)b * NCP;
        for (int j = tid; j < NC; j += PTHR) curs[j] = mc[j];
        __syncthreads();
        int base = b * CEPB;
        for (int i = tid; i < CEPB; i += PTHR) {
            int e = base + i;
            int r = row[e];
            int c = col[e];
            float we = w[e];
            int p = atomicAdd(&curs[c >> 8], 1);   // LDS atomic only
            recA[p] = make_int2(((c & 255) << 17) | r, __float_as_int(we));
        }
    }
    gridbar(bar, PBLK);

    // ---- Phase E2: in-place fine sort per coarse bucket; fold dinv[row]*w ----
    {
        int2* buf  = (int2*)smem;                   // 40960 B
        int*  h    = (int*)(smem + CAPC * 8);       // 256
        int*  cu   = h + 256;                       // 256
        int*  wsum = cu + 256;                      // 8
        for (int cb = b; cb < NC; cb += PBLK) {
            int base = cbase[cb];
            int cnt = min(cbase[cb + 1] - base, CAPC);
            if (tid < 256) h[tid] = 0;
            __syncthreads();
            for (int i = tid; i < cnt; i += PTHR)
                atomicAdd(&h[(recA[base + i].x >> 17) & 255], 1);
            __syncthreads();
            int v = 0, inc = 0;
            if (tid < 256) {
                v = h[tid];
                inc = v;
                int lane = tid & 63;
                #pragma unroll
                for (int d2 = 1; d2 < 64; d2 <<= 1) {
                    int u = __shfl_up(inc, d2, 64);
                    if (lane >= d2) inc += u;
                }
                if (lane == 63) wsum[tid >> 6] = inc;
            }
            __syncthreads();
            if (tid < 256) {
                int woff = 0;
                for (int w2 = 0; w2 < (tid >> 6); ++w2) woff += wsum[w2];
                int st = woff + inc - v;            // exclusive start, fine slot tid
                cu[tid] = st;
                int nid = cb * 256 + tid;
                if (nid <= N_NODES) node_start[nid] = base + st;
            }
            __syncthreads();
            for (int i = tid; i < cnt; i += PTHR) {
                int2 rc = recA[base + i];
                int r = rc.x & 0x1FFFF;
                float cf = __int_as_float(rc.y) * dinv[r];
                int p = atomicAdd(&cu[(rc.x >> 17) & 255], 1);
                buf[p] = make_int2(r, __float_as_int(cf));
            }
            __syncthreads();
            for (int i = tid; i < cnt; i += PTHR) recA[base + i] = buf[i];
            __syncthreads();                        // h/buf reused next iter
        }
    }
}

#define FMA_BF16(e, u)                                                         \
    do { float cc = __int_as_float((e).y);                                     \
        acc0.x += cc * __uint_as_float((u).x << 16);                           \
        acc0.y += cc * __uint_as_float((u).x & 0xFFFF0000u);                   \
        acc0.z += cc * __uint_as_float((u).y << 16);                           \
        acc0.w += cc * __uint_as_float((u).y & 0xFFFF0000u);                   \
        acc1.x += cc * __uint_as_float((u).z << 16);                           \
        acc1.y += cc * __uint_as_float((u).z & 0xFFFF0000u);                   \
        acc1.z += cc * __uint_as_float((u).w << 16);                           \
        acc1.w += cc * __uint_as_float((u).w & 0xFFFF0000u);                   \
    } while (0)

// ---- K1: gather from sorted records (r2-verbatim, measured 127.4 us) ----
__global__ __launch_bounds__(256, 8) void gather_out_kernel(
        const int2* __restrict__ recS, const int* __restrict__ node_start,
        const float* __restrict__ dinv, const ushort* __restrict__ xh,
        const float* __restrict__ x, const float* __restrict__ W0,
        const float* __restrict__ W1, const float* __restrict__ bias,
        float* __restrict__ out) {
    __shared__ __align__(16) char smemA[32 * AST * 4];  // stg (6144B) | xs (8704B)
    __shared__ __align__(16) char smemB[32 * AST * 4];  // ts
    __shared__ int s33[33];
    int2*  stg = (int2*)smemA;
    float* xs  = (float*)smemA;
    float* ts  = (float*)smemB;

    int tid = threadIdx.x;
    int b   = blockIdx.x;
    int n0  = b * 32;
    int g   = tid >> 3;      // node within bucket
    int j   = tid & 7;       // lane owns features 8j..8j+7

    if (tid < 33) s33[tid] = node_start[n0 + tid];
    __syncthreads();
    int base = s33[0];
    int cnt  = s33[32] - base;
    int ks   = s33[g];
    int ke   = s33[g + 1];

    float4 acc0 = make_float4(0.f, 0.f, 0.f, 0.f);
    float4 acc1 = make_float4(0.f, 0.f, 0.f, 0.f);
    const ushort* xhj = xh + (j << 3);

    for (int off = 0; off < cnt; off += SCAP) {
        int m = min(SCAP, cnt - off);
        for (int i = tid; i < m; i += 256) stg[i] = recS[base + off + i];  // coalesced
        __syncthreads();
        int k0 = max(ks - base - off, 0);
        int k1 = min(ke - base - off, m);
        int k = k0;
        for (; k + 3 < k1; k += 4) {
            int2 e0 = stg[k + 0];
            int2 e1 = stg[k + 1];
            int2 e2 = stg[k + 2];
            int2 e3 = stg[k + 3];
            uint4 u0 = *(const uint4*)(xhj + ((size_t)e0.x << 6));
            uint4 u1 = *(const uint4*)(xhj + ((size_t)e1.x << 6));
            uint4 u2 = *(const uint4*)(xhj + ((size_t)e2.x << 6));
            uint4 u3 = *(const uint4*)(xhj + ((size_t)e3.x << 6));
            FMA_BF16(e0, u0);
            FMA_BF16(e1, u1);
            FMA_BF16(e2, u2);
            FMA_BF16(e3, u3);
        }
        for (; k < k1; ++k) {
            int2 e0 = stg[k];
            uint4 u0 = *(const uint4*)(xhj + ((size_t)e0.x << 6));
            FMA_BF16(e0, u0);
        }
        __syncthreads();   // stg reads done before next chunk / xs overwrite
    }

    // Epilogue: ts = -dinv[n]*acc, stage xs (fp32), matmul.
    float dn = -dinv[n0 + g];
    float* tp = ts + g * AST + (j << 3);
    *(float4*)tp       = make_float4(dn * acc0.x, dn * acc0.y, dn * acc0.z, dn * acc0.w);
    *(float4*)(tp + 4) = make_float4(dn * acc1.x, dn * acc1.y, dn * acc1.z, dn * acc1.w);
    for (int i = tid; i < 512; i += 256) {          // 512 float4 = 32x64 floats
        int nn = i >> 4;
        int kk = (i & 15) << 2;
        *(float4*)&xs[nn * AST + kk] = *(const float4*)(x + (size_t)n0 * D + i * 4);
    }
    __syncthreads();

    int jl = j << 3;
    float4 o0 = *(const float4*)(bias + jl);
    float4 o1 = *(const float4*)(bias + jl + 4);
    for (int k2 = 0; k2 < D; k2 += 4) {
        float4 av = *(const float4*)&xs[g * AST + k2];
        float4 tv = *(const float4*)&ts[g * AST + k2];
        #pragma unroll
        for (int u = 0; u < 4; ++u) {
            float a = (u == 0) ? av.x : (u == 1) ? av.y : (u == 2) ? av.z : av.w;
            float t = (u == 0) ? tv.x : (u == 1) ? tv.y : (u == 2) ? tv.z : tv.w;
            const float4 w00 = *(const float4*)(W0 + (size_t)(k2 + u) * D + jl);
            const float4 w01 = *(const float4*)(W0 + (size_t)(k2 + u) * D + jl + 4);
            const float4 w10 = *(const float4*)(W1 + (size_t)(k2 + u) * D + jl);
            const float4 w11 = *(const float4*)(W1 + (size_t)(k2 + u) * D + jl + 4);
            o0.x += a * w00.x + t * w10.x;
            o0.y += a * w00.y + t * w10.y;
            o0.z += a * w00.z + t * w10.z;
            o0.w += a * w00.w + t * w10.w;
            o1.x += a * w01.x + t * w11.x;
            o1.y += a * w01.y + t * w11.y;
            o1.z += a * w01.z + t * w11.z;
            o1.w += a * w01.w + t * w11.w;
        }
    }
    float* op = out + (size_t)(n0 + g) * D + jl;
    *(float4*)op       = o0;
    *(float4*)(op + 4) = o1;
}

extern "C" void kernel_launch(void* const* d_in, const int* in_sizes, int n_in,
                              void* d_out, int out_size, void* d_ws, size_t ws_size,
                              hipStream_t stream) {
    const float* x    = (const float*)d_in[0];
    const int*   eidx = (const int*)d_in[1];   // [2, E]: row then col (int32)
    const float* ew   = (const float*)d_in[2];
    const float* W0   = (const float*)d_in[3];
    const float* W1   = (const float*)d_in[4];
    const float* b    = (const float*)d_in[5];
    float* out = (float*)d_out;

    const int* row = eidx;
    const int* col = eidx + N_EDGES;

    // Workspace (4B words), fully overwritten each call (bar memset below):
    // recA 12.8MB | cntC 200KB | btot/cbase 3.2KB | bar 16B | deg 0.4MB |
    // dinv 0.4MB | node_start 0.4MB | xh 12.8MB  ~= 27.1MB
    int2*   recA  = (int2*)d_ws;                               // E int2
    int*    cntC  = (int*)(recA + N_EDGES);                    // CBLK*NCP
    int*    btot  = cntC + (size_t)CBLK * NCP;                 // NC (pad 400)
    int*    cbase = btot + 400;                                // NC+1 (pad 400)
    int*    bar   = cbase + 400;                               // 2 (pad 4)
    float*  deg   = (float*)(bar + 4);                         // N
    float*  dinv  = deg + N_NODES;                             // N
    int*    node_start = (int*)(dinv + N_NODES);               // N+1 (pad 100016)
    ushort* xh    = (ushort*)(node_start + 100016);            // N*D ushort

    hipMemsetAsync(bar, 0, 2 * sizeof(int), stream);
    fused_pre<<<PBLK, PTHR, 0, stream>>>(x, row, col, ew, xh, deg, cntC, btot,
                                         cbase, dinv, recA, node_start, bar);
    gather_out_kernel<<<N_NODES / 32, 256, 0, stream>>>(recA, node_start, dinv,
                                                        xh, x, W0, W1, b, out);
}

// Round 7
// 326.739 us; speedup vs baseline: 3.9818x; 3.9818x over previous
//
#include <hip/hip_runtime.h>

#define N_NODES 100000
#define N_EDGES 1600000
#define D 64
#define NB 128               // edge-chunk blocks for count/scatter
#define EPB (N_EDGES / NB)   // 12500 edges per block
#define NBUCK 3125           // 100000 >> 5 buckets of 32 nodes
#define NBUCK_PAD 3136       // 32-multiple padding (98 groups of 32)
#define NGRP 98              // NBUCK_PAD / 32
#define CAP 1024             // records per in-LDS sort chunk (buckets avg ~512)
#define AST 68               // padded LDS row stride (bank-conflict-free)

// -------- K0: x (fp32) -> xh (bf16, RNE); zero the 4 deg shadows ----------
__device__ __forceinline__ unsigned bf16rne(float f) {
    unsigned u = __float_as_uint(f);
    return (u + 0x7FFFu + ((u >> 16) & 1u)) >> 16;
}
__global__ __launch_bounds__(256) void tobf16_kernel(const float* __restrict__ x,
                                                     ushort* __restrict__ xh,
                                                     float* __restrict__ deg4) {
    int id = blockIdx.x * 256 + threadIdx.x;        // 800k threads
    if (id < 4 * N_NODES) deg4[id] = 0.f;
    int i = id * 8;                                 // 6.4M elems / 8
    float4 a = *(const float4*)(x + i);
    float4 b = *(const float4*)(x + i + 4);
    uint4 o;
    o.x = bf16rne(a.x) | (bf16rne(a.y) << 16);
    o.y = bf16rne(a.z) | (bf16rne(a.w) << 16);
    o.z = bf16rne(b.x) | (bf16rne(b.y) << 16);
    o.w = bf16rne(b.z) | (bf16rne(b.w) << 16);
    *(uint4*)(xh + i) = o;
}

// -------- K1: per-block col-bucket counts + deg shadow atomics ------------
__global__ __launch_bounds__(512) void count_kernel(const int* __restrict__ row,
                                                    const int* __restrict__ col,
                                                    const float* __restrict__ w,
                                                    float* __restrict__ deg4,
                                                    int* __restrict__ matC) {
    __shared__ int cC[NBUCK_PAD];
    int t = threadIdx.x;
    for (int j = t; j < NBUCK_PAD; j += 512) cC[j] = 0;
    __syncthreads();
    int base = blockIdx.x * EPB;
    float* dg = deg4 + (size_t)(blockIdx.x & 3) * N_NODES;
    for (int i = t; i < EPB; i += 512) {
        int e = base + i;
        atomicAdd(&dg[row[e]], w[e]);               // fire-and-forget, 4 shadows
        atomicAdd(&cC[col[e] >> 5], 1);
    }
    __syncthreads();
    int* mc = matC + (size_t)blockIdx.x * NBUCK_PAD;
    for (int j = t; j < NBUCK_PAD; j += 512) mc[j] = cC[j];
}

// -------- K2: tiled per-bucket exclusive scan over NB blocks (in place) ---
__global__ __launch_bounds__(256) void blockscan_kernel(int* __restrict__ matC,
                                                        int* __restrict__ totalsC) {
    int grp = blockIdx.x;
    int j0 = grp * 32;
    __shared__ int tile[NB][33];
    int t = threadIdx.x;
    int r = t >> 1;          // 0..127
    int h = t & 1;           // 0..1
    {
        const int* src = matC + (size_t)r * NBUCK_PAD + j0 + h * 16;
        int4 v0 = *(const int4*)(src + 0);
        int4 v1 = *(const int4*)(src + 4);
        int4 v2 = *(const int4*)(src + 8);
        int4 v3 = *(const int4*)(src + 12);
        int cb = h * 16;
        tile[r][cb+0]=v0.x;  tile[r][cb+1]=v0.y;  tile[r][cb+2]=v0.z;  tile[r][cb+3]=v0.w;
        tile[r][cb+4]=v1.x;  tile[r][cb+5]=v1.y;  tile[r][cb+6]=v1.z;  tile[r][cb+7]=v1.w;
        tile[r][cb+8]=v2.x;  tile[r][cb+9]=v2.y;  tile[r][cb+10]=v2.z; tile[r][cb+11]=v2.w;
        tile[r][cb+12]=v3.x; tile[r][cb+13]=v3.y; tile[r][cb+14]=v3.z; tile[r][cb+15]=v3.w;
    }
    __syncthreads();
    int g = t >> 3;          // bucket within tile, 0..31
    int l = t & 7;           // lane in 8-wide scan group
    int rows0 = l * 16;
    int vals[16];
    int s = 0;
    #pragma unroll
    for (int i = 0; i < 16; ++i) { vals[i] = tile[rows0 + i][g]; s += vals[i]; }
    int inc = s;
    #pragma unroll
    for (int d = 1; d < 8; d <<= 1) {
        int u = __shfl_up(inc, d, 8);
        if (l >= d) inc += u;
    }
    int excl = inc - s;
    #pragma unroll
    for (int i = 0; i < 16; ++i) { int e2 = excl; excl += vals[i]; tile[rows0 + i][g] = e2; }
    if (l == 7) totalsC[j0 + g] = inc;
    __syncthreads();
    {
        int* dst = matC + (size_t)r * NBUCK_PAD + j0 + h * 16;
        int cb = h * 16;
        int4 v0 = make_int4(tile[r][cb+0],  tile[r][cb+1],  tile[r][cb+2],  tile[r][cb+3]);
        int4 v1 = make_int4(tile[r][cb+4],  tile[r][cb+5],  tile[r][cb+6],  tile[r][cb+7]);
        int4 v2 = make_int4(tile[r][cb+8],  tile[r][cb+9],  tile[r][cb+10], tile[r][cb+11]);
        int4 v3 = make_int4(tile[r][cb+12], tile[r][cb+13], tile[r][cb+14], tile[r][cb+15]);
        *(int4*)(dst + 0)  = v0;
        *(int4*)(dst + 4)  = v1;
        *(int4*)(dst + 8)  = v2;
        *(int4*)(dst + 12) = v3;
    }
}

// -------- K3: exclusive scan of bucket totals (one block) -----------------
__global__ __launch_bounds__(256) void totscan_kernel(const int* __restrict__ totalsC,
                                                      int* __restrict__ bstartC) {
    const int CH = (NBUCK_PAD + 255) / 256;  // 13
    __shared__ int lds[256];
    int t = threadIdx.x;
    int local[CH];
    int s = 0;
    for (int i = 0; i < CH; ++i) {
        int idx = t * CH + i;
        local[i] = (idx < NBUCK_PAD) ? totalsC[idx] : 0;
        s += local[i];
    }
    lds[t] = s;
    __syncthreads();
    for (int off = 1; off < 256; off <<= 1) {
        int u = (t >= off) ? lds[t - off] : 0;
        __syncthreads();
        lds[t] += u;
        __syncthreads();
    }
    int excl = (t > 0) ? lds[t - 1] : 0;
    for (int i = 0; i < CH; ++i) {
        int idx = t * CH + i;
        if (idx < NBUCK_PAD) bstartC[idx] = excl;
        excl += local[i];
    }
}

// -------- K4: scatter edges into bucket order, LDS cursors ----------------
// crec = row<<15 | coloff<<10 | w_q10   (4B, col-bucket order)
__global__ __launch_bounds__(512) void scatter_kernel(const int* __restrict__ row,
                                                      const int* __restrict__ col,
                                                      const float* __restrict__ w,
                                                      const int* __restrict__ matC,
                                                      const int* __restrict__ bstartC,
                                                      unsigned* __restrict__ crecs) {
    __shared__ int cursC[NBUCK];
    int t = threadIdx.x;
    const int* offC = matC + (size_t)blockIdx.x * NBUCK_PAD;
    for (int j = t; j < NBUCK; j += 512) cursC[j] = bstartC[j] + offC[j];
    __syncthreads();
    int base = blockIdx.x * EPB;
    for (int i = t; i < EPB; i += 512) {
        int e = base + i;
        int r = row[e];
        int c = col[e];
        float we = w[e];
        unsigned wq = (unsigned)min(1023, (int)(we * 1024.f + 0.5f));
        int pC = atomicAdd(&cursC[c >> 5], 1);
        crecs[pC] = ((unsigned)r << 15) | ((unsigned)(c & 31) << 10) | wq;
    }
}

// -------- K5: deg shadows -> dinv --------
__global__ __launch_bounds__(256) void dinv_kernel(const float* __restrict__ deg4,
                                                   float* __restrict__ dinv) {
    int i = (blockIdx.x * 256 + threadIdx.x) * 4;
    if (i >= N_NODES) return;                      // N_NODES % 4 == 0
    float4 a = *(const float4*)(deg4 + i);
    float4 b = *(const float4*)(deg4 + N_NODES + i);
    float4 c = *(const float4*)(deg4 + 2 * N_NODES + i);
    float4 d = *(const float4*)(deg4 + 3 * N_NODES + i);
    float sx = a.x + b.x + c.x + d.x;
    float sy = a.y + b.y + c.y + d.y;
    float sz = a.z + b.z + c.z + d.z;
    float sw = a.w + b.w + c.w + d.w;
    float4 o;
    o.x = sx > 0.f ? rsqrtf(sx) : 0.f;
    o.y = sy > 0.f ? rsqrtf(sy) : 0.f;
    o.z = sz > 0.f ? rsqrtf(sz) : 0.f;
    o.w = sw > 0.f ? rsqrtf(sw) : 0.f;
    *(float4*)(dinv + i) = o;
}

#define FMA_BF16(e, u)                                                         \
    do { float cc = __int_as_float((e).y);                                     \
        acc0.x += cc * __uint_as_float((u).x << 16);                           \
        acc0.y += cc * __uint_as_float((u).x & 0xFFFF0000u);                   \
        acc0.z += cc * __uint_as_float((u).y << 16);                           \
        acc0.w += cc * __uint_as_float((u).y & 0xFFFF0000u);                   \
        acc1.x += cc * __uint_as_float((u).z << 16);                           \
        acc1.y += cc * __uint_as_float((u).z & 0xFFFF0000u);                   \
        acc1.z += cc * __uint_as_float((u).w << 16);                           \
        acc1.w += cc * __uint_as_float((u).w & 0xFFFF0000u);                   \
    } while (0)

// -------- K6: fused sort + per-node register gather (bf16 x) + matmul ------
// Block = one bucket of 32 nodes; 256 threads = 32 node-groups x 8 lanes.
// Round-0 verbatim (measured 127.8 us).
__global__ __launch_bounds__(256) void gather_out_kernel(
        const unsigned* __restrict__ crecs, const int* __restrict__ bstartC,
        const int* __restrict__ totalsC, const float* __restrict__ dinv,
        const ushort* __restrict__ xh, const float* __restrict__ x,
        const float* __restrict__ W0, const float* __restrict__ W1,
        const float* __restrict__ bias, float* __restrict__ out) {
    __shared__ __align__(16) char smemA[32 * AST * 4];  // srt (8192B) | xs
    __shared__ __align__(16) char smemB[32 * AST * 4];  // ts
    __shared__ int cnt32[32];
    __shared__ int start32[32];
    __shared__ int cur32[32];
    int2*  srt = (int2*)smemA;
    float* xs  = (float*)smemA;
    float* ts  = (float*)smemB;

    int tid = threadIdx.x;
    int b   = blockIdx.x;
    int n0  = b * 32;
    int g   = tid >> 3;      // node within bucket
    int j   = tid & 7;       // lane owns features 8j..8j+7

    int base = bstartC[b];
    int cnt  = totalsC[b];

    float4 acc0 = make_float4(0.f, 0.f, 0.f, 0.f);
    float4 acc1 = make_float4(0.f, 0.f, 0.f, 0.f);
    const ushort* xhj = xh + (j << 3);

    for (int cb = 0; cb < cnt; cb += CAP) {
        int m = min(CAP, cnt - cb);
        if (tid < 32) cnt32[tid] = 0;
        __syncthreads();
        // pass 1: count by coloff (sequential 4B reads; L2-hot for pass 2)
        for (int i = tid; i < m; i += 256)
            atomicAdd(&cnt32[(crecs[base + cb + i] >> 10) & 31u], 1);
        __syncthreads();
        if (tid < 32) {               // exclusive scan via shfl (wave 0)
            int v = cnt32[tid];
            int inc = v;
            #pragma unroll
            for (int d = 1; d < 32; d <<= 1) {
                int u = __shfl_up(inc, d, 32);
                if (tid >= d) inc += u;
            }
            start32[tid] = inc - v;
            cur32[tid]   = inc - v;
        }
        __syncthreads();
        // pass 2: decode + place (dinv[r] and dequant folded into weight)
        for (int i = tid; i < m; i += 256) {
            unsigned u = crecs[base + cb + i];
            int r = u >> 15;
            float cf = (float)(u & 1023u) * (1.f / 1024.f) * dinv[r];
            int p = atomicAdd(&cur32[(u >> 10) & 31u], 1);
            srt[p] = make_int2(r, __float_as_int(cf));
        }
        __syncthreads();
        // per-node accumulation from bf16 rows (1 uint4 = 8 features / edge)
        int ks = start32[g];
        int ke = cur32[g];
        int k = ks;
        for (; k + 3 < ke; k += 4) {
            int2 e0 = srt[k + 0];
            int2 e1 = srt[k + 1];
            int2 e2 = srt[k + 2];
            int2 e3 = srt[k + 3];
            uint4 u0 = *(const uint4*)(xhj + ((size_t)e0.x << 6));
            uint4 u1 = *(const uint4*)(xhj + ((size_t)e1.x << 6));
            uint4 u2 = *(const uint4*)(xhj + ((size_t)e2.x << 6));
            uint4 u3 = *(const uint4*)(xhj + ((size_t)e3.x << 6));
            FMA_BF16(e0, u0);
            FMA_BF16(e1, u1);
            FMA_BF16(e2, u2);
            FMA_BF16(e3, u3);
        }
        for (; k < ke; ++k) {
            int2 e0 = srt[k];
            uint4 u0 = *(const uint4*)(xhj + ((size_t)e0.x << 6));
            FMA_BF16(e0, u0);
        }
        __syncthreads();   // srt reads done before next chunk / xs overwrite
    }

    // Phase C: ts = -dinv[n]*acc, stage xs (fp32), matmul epilogue.
    float dn = -dinv[n0 + g];
    float* tp = ts + g * AST + (j << 3);
    *(float4*)tp       = make_float4(dn * acc0.x, dn * acc0.y, dn * acc0.z, dn * acc0.w);
    *(float4*)(tp + 4) = make_float4(dn * acc1.x, dn * acc1.y, dn * acc1.z, dn * acc1.w);
    for (int i = tid; i < 512; i += 256) {          // 512 float4 = 32x64 floats
        int nn = i >> 4;
        int kk = (i & 15) << 2;
        *(float4*)&xs[nn * AST + kk] = *(const float4*)(x + (size_t)n0 * D + i * 4);
    }
    __syncthreads();

    int jl = j << 3;
    float4 o0 = *(const float4*)(bias + jl);
    float4 o1 = *(const float4*)(bias + jl + 4);
    for (int k = 0; k < D; k += 4) {
        float4 av = *(const float4*)&xs[g * AST + k];
        float4 tv = *(const float4*)&ts[g * AST + k];
        #pragma unroll
        for (int u = 0; u < 4; ++u) {
            float a = (u == 0) ? av.x : (u == 1) ? av.y : (u == 2) ? av.z : av.w;
            float t = (u == 0) ? tv.x : (u == 1) ? tv.y : (u == 2) ? tv.z : tv.w;
            const float4 w00 = *(const float4*)(W0 + (size_t)(k + u) * D + jl);
            const float4 w01 = *(const float4*)(W0 + (size_t)(k + u) * D + jl + 4);
            const float4 w10 = *(const float4*)(W1 + (size_t)(k + u) * D + jl);
            const float4 w11 = *(const float4*)(W1 + (size_t)(k + u) * D + jl + 4);
            o0.x += a * w00.x + t * w10.x;
            o0.y += a * w00.y + t * w10.y;
            o0.z += a * w00.z + t * w10.z;
            o0.w += a * w00.w + t * w10.w;
            o1.x += a * w01.x + t * w11.x;
            o1.y += a * w01.y + t * w11.y;
            o1.z += a * w01.z + t * w11.z;
            o1.w += a * w01.w + t * w11.w;
        }
    }
    float* op = out + (size_t)(n0 + g) * D + jl;
    *(float4*)op       = o0;
    *(float4*)(op + 4) = o1;
}

extern "C" void kernel_launch(void* const* d_in, const int* in_sizes, int n_in,
                              void* d_out, int out_size, void* d_ws, size_t ws_size,
                              hipStream_t stream) {
    const float* x    = (const float*)d_in[0];
    const int*   eidx = (const int*)d_in[1];   // [2, E]: row then col
    const float* ew   = (const float*)d_in[2];
    const float* W0   = (const float*)d_in[3];
    const float* W1   = (const float*)d_in[4];
    const float* b    = (const float*)d_in[5];
    float* out = (float*)d_out;

    const int* row = eidx;
    const int* col = eidx + N_EDGES;

    // Workspace (4B words), fully overwritten each call, no memset.
    // crecs 6.4MB | matC 1.6MB | totalsC/bstartC 25KB | deg4 1.6MB |
    // dinv 0.4MB | xh 12.8MB  ~= 22.9MB
    unsigned* crecs   = (unsigned*)d_ws;                               // E
    int*      matC    = (int*)(crecs + N_EDGES);                       // NB*NBUCK_PAD
    int*      totalsC = matC + (size_t)NB * NBUCK_PAD;                 // NBUCK_PAD
    int*      bstartC = totalsC + NBUCK_PAD;                           // NBUCK_PAD
    float*    deg4    = (float*)(bstartC + NBUCK_PAD);                 // 4*N
    float*    dinv    = deg4 + 4 * N_NODES;                            // N
    ushort*   xh      = (ushort*)(dinv + N_NODES);                     // N*D ushort

    tobf16_kernel    <<<N_NODES * D / (256 * 8), 256, 0, stream>>>(x, xh, deg4);
    count_kernel     <<<NB, 512, 0, stream>>>(row, col, ew, deg4, matC);
    blockscan_kernel <<<NGRP, 256, 0, stream>>>(matC, totalsC);
    totscan_kernel   <<<1, 256, 0, stream>>>(totalsC, bstartC);
    scatter_kernel   <<<NB, 512, 0, stream>>>(row, col, ew, matC, bstartC, crecs);
    dinv_kernel      <<<98, 256, 0, stream>>>(deg4, dinv);
    gather_out_kernel<<<NBUCK, 256, 0, stream>>>(crecs, bstartC, totalsC, dinv,
                                                 xh, x, W0, W1, b, out);
}

// Round 8
// 295.554 us; speedup vs baseline: 4.4020x; 1.1055x over previous
//
#include <hip/hip_runtime.h>

#define N_NODES 100000
#define N_EDGES 1600000
#define D 64
#define NB 128               // edge-chunk blocks for count/scatter
#define EPB (N_EDGES / NB)   // 12500 edges per block
#define NBUCK 3125           // 100000 >> 5 buckets of 32 nodes
#define NBUCK_PAD 3136       // 32-multiple padding (98 groups of 32)
#define NGRP 98              // NBUCK_PAD / 32
#define CAP 1024             // records per in-LDS sort chunk (buckets avg ~512)
#define AST 68               // padded LDS row stride (bank-conflict-free)

// -------- K0: x (fp32) -> xh (bf16, RNE) --------
__device__ __forceinline__ unsigned bf16rne(float f) {
    unsigned u = __float_as_uint(f);
    return (u + 0x7FFFu + ((u >> 16) & 1u)) >> 16;
}
__global__ __launch_bounds__(256) void tobf16_kernel(const float* __restrict__ x,
                                                     ushort* __restrict__ xh) {
    int i = (blockIdx.x * 256 + threadIdx.x) * 8;   // 6.4M elems / 8 = 800k threads
    float4 a = *(const float4*)(x + i);
    float4 b = *(const float4*)(x + i + 4);
    uint4 o;
    o.x = bf16rne(a.x) | (bf16rne(a.y) << 16);
    o.y = bf16rne(a.z) | (bf16rne(a.w) << 16);
    o.z = bf16rne(b.x) | (bf16rne(b.y) << 16);
    o.w = bf16rne(b.z) | (bf16rne(b.w) << 16);
    *(uint4*)(xh + i) = o;
}

// -------- K1: per-block coarse counts (col-buckets and row-buckets) --------
__global__ __launch_bounds__(512) void count_kernel(const int* __restrict__ row,
                                                    const int* __restrict__ col,
                                                    int* __restrict__ matC,
                                                    int* __restrict__ matR) {
    __shared__ int cC[NBUCK_PAD];
    __shared__ int cR[NBUCK_PAD];
    int t = threadIdx.x;
    for (int j = t; j < NBUCK_PAD; j += 512) { cC[j] = 0; cR[j] = 0; }
    __syncthreads();
    int base = blockIdx.x * EPB;
    for (int i = t; i < EPB; i += 512) {
        int e = base + i;
        atomicAdd(&cC[col[e] >> 5], 1);
        atomicAdd(&cR[row[e] >> 5], 1);
    }
    __syncthreads();
    int* mc = matC + (size_t)blockIdx.x * NBUCK_PAD;
    int* mr = matR + (size_t)blockIdx.x * NBUCK_PAD;
    for (int j = t; j < NBUCK_PAD; j += 512) { mc[j] = cC[j]; mr[j] = cR[j]; }
}

// -------- K2a: tiled per-bucket exclusive scan over NB blocks (in place) ---
__global__ __launch_bounds__(256) void blockscan_kernel(int* __restrict__ matC,
                                                        int* __restrict__ matR,
                                                        int* __restrict__ totalsC,
                                                        int* __restrict__ totalsR) {
    int which = blockIdx.x / NGRP;
    int grp   = blockIdx.x % NGRP;
    int* mat    = which ? matR : matC;
    int* totals = which ? totalsR : totalsC;
    int j0 = grp * 32;
    __shared__ int tile[NB][33];
    int t = threadIdx.x;
    int r = t >> 1;          // 0..127
    int h = t & 1;           // 0..1
    {
        const int* src = mat + (size_t)r * NBUCK_PAD + j0 + h * 16;
        int4 v0 = *(const int4*)(src + 0);
        int4 v1 = *(const int4*)(src + 4);
        int4 v2 = *(const int4*)(src + 8);
        int4 v3 = *(const int4*)(src + 12);
        int cb = h * 16;
        tile[r][cb+0]=v0.x;  tile[r][cb+1]=v0.y;  tile[r][cb+2]=v0.z;  tile[r][cb+3]=v0.w;
        tile[r][cb+4]=v1.x;  tile[r][cb+5]=v1.y;  tile[r][cb+6]=v1.z;  tile[r][cb+7]=v1.w;
        tile[r][cb+8]=v2.x;  tile[r][cb+9]=v2.y;  tile[r][cb+10]=v2.z; tile[r][cb+11]=v2.w;
        tile[r][cb+12]=v3.x; tile[r][cb+13]=v3.y; tile[r][cb+14]=v3.z; tile[r][cb+15]=v3.w;
    }
    __syncthreads();
    int g = t >> 3;          // bucket within tile, 0..31
    int l = t & 7;           // lane in 8-wide scan group
    int rows0 = l * 16;
    int vals[16];
    int s = 0;
    #pragma unroll
    for (int i = 0; i < 16; ++i) { vals[i] = tile[rows0 + i][g]; s += vals[i]; }
    int inc = s;
    #pragma unroll
    for (int d = 1; d < 8; d <<= 1) {
        int u = __shfl_up(inc, d, 8);
        if (l >= d) inc += u;
    }
    int excl = inc - s;
    #pragma unroll
    for (int i = 0; i < 16; ++i) { int e2 = excl; excl += vals[i]; tile[rows0 + i][g] = e2; }
    if (l == 7) totals[j0 + g] = inc;
    __syncthreads();
    {
        int* dst = mat + (size_t)r * NBUCK_PAD + j0 + h * 16;
        int cb = h * 16;
        int4 v0 = make_int4(tile[r][cb+0],  tile[r][cb+1],  tile[r][cb+2],  tile[r][cb+3]);
        int4 v1 = make_int4(tile[r][cb+4],  tile[r][cb+5],  tile[r][cb+6],  tile[r][cb+7]);
        int4 v2 = make_int4(tile[r][cb+8],  tile[r][cb+9],  tile[r][cb+10], tile[r][cb+11]);
        int4 v3 = make_int4(tile[r][cb+12], tile[r][cb+13], tile[r][cb+14], tile[r][cb+15]);
        *(int4*)(dst + 0)  = v0;
        *(int4*)(dst + 4)  = v1;
        *(int4*)(dst + 8)  = v2;
        *(int4*)(dst + 12) = v3;
    }
}

// -------- K2b: exclusive scan of bucket totals (one block per array) -------
__global__ __launch_bounds__(256) void totscan_kernel(const int* __restrict__ totalsC,
                                                      int* __restrict__ bstartC,
                                                      const int* __restrict__ totalsR,
                                                      int* __restrict__ bstartR) {
    const int* tot = blockIdx.x ? totalsR : totalsC;
    int* bst       = blockIdx.x ? bstartR : bstartC;
    const int CH = (NBUCK_PAD + 255) / 256;  // 13
    __shared__ int lds[256];
    int t = threadIdx.x;
    int local[CH];
    int s = 0;
    for (int i = 0; i < CH; ++i) {
        int idx = t * CH + i;
        local[i] = (idx < NBUCK_PAD) ? tot[idx] : 0;
        s += local[i];
    }
    lds[t] = s;
    __syncthreads();
    for (int off = 1; off < 256; off <<= 1) {
        int u = (t >= off) ? lds[t - off] : 0;
        __syncthreads();
        lds[t] += u;
        __syncthreads();
    }
    int excl = (t > 0) ? lds[t - 1] : 0;
    for (int i = 0; i < CH; ++i) {
        int idx = t * CH + i;
        if (idx < NBUCK_PAD) bst[idx] = excl;
        excl += local[i];
    }
}

// -------- K3: scatter edges into bucket order, LDS cursors, NO globals -----
// crec = row<<15 | coloff<<10 | w_q10   (4B, col-bucket order)
// rrec = (bits(w) & ~31) | (row&31)     (4B, row-bucket order)
__global__ __launch_bounds__(512) void scatter_kernel(const int* __restrict__ row,
                                                      const int* __restrict__ col,
                                                      const float* __restrict__ w,
                                                      const int* __restrict__ matC,
                                                      const int* __restrict__ matR,
                                                      const int* __restrict__ bstartC,
                                                      const int* __restrict__ bstartR,
                                                      unsigned* __restrict__ crecs,
                                                      unsigned* __restrict__ rrecs) {
    __shared__ int cursC[NBUCK];
    __shared__ int cursR[NBUCK];
    int t = threadIdx.x;
    const int* offC = matC + (size_t)blockIdx.x * NBUCK_PAD;
    const int* offR = matR + (size_t)blockIdx.x * NBUCK_PAD;
    for (int j = t; j < NBUCK; j += 512) {
        cursC[j] = bstartC[j] + offC[j];
        cursR[j] = bstartR[j] + offR[j];
    }
    __syncthreads();
    int base = blockIdx.x * EPB;
    for (int i = t; i < EPB; i += 512) {
        int e = base + i;
        int r = row[e];
        int c = col[e];
        float we = w[e];
        unsigned wq = (unsigned)min(1023, (int)(we * 1024.f + 0.5f));
        int pC = atomicAdd(&cursC[c >> 5], 1);
        crecs[pC] = ((unsigned)r << 15) | ((unsigned)(c & 31) << 10) | wq;
        int pR = atomicAdd(&cursR[r >> 5], 1);
        rrecs[pR] = (__float_as_uint(we) & ~31u) | (unsigned)(r & 31);
    }
}

// -------- K4: per row-bucket degree reduction -> dinv --------
__global__ __launch_bounds__(256) void deg_kernel(const unsigned* __restrict__ rrecs,
                                                  const int* __restrict__ bstartR,
                                                  const int* __restrict__ totalsR,
                                                  float* __restrict__ dinv) {
    __shared__ float acc[32];
    int t = threadIdx.x;
    int b = blockIdx.x;
    if (t < 32) acc[t] = 0.f;
    __syncthreads();
    int base = bstartR[b];
    int cnt  = totalsR[b];
    for (int i = t; i < cnt; i += 256) {
        unsigned v = rrecs[base + i];
        atomicAdd(&acc[v & 31u], __uint_as_float(v & ~31u));
    }
    __syncthreads();
    if (t < 32) {
        float d = acc[t];
        dinv[b * 32 + t] = d > 0.f ? rsqrtf(d) : 0.f;
    }
}

#define FMA_BF16(e, u)                                                         \
    do { float cc = __int_as_float((e).y);                                     \
        acc0.x += cc * __uint_as_float((u).x << 16);                           \
        acc0.y += cc * __uint_as_float((u).x & 0xFFFF0000u);                   \
        acc0.z += cc * __uint_as_float((u).y << 16);                           \
        acc0.w += cc * __uint_as_float((u).y & 0xFFFF0000u);                   \
        acc1.x += cc * __uint_as_float((u).z << 16);                           \
        acc1.y += cc * __uint_as_float((u).z & 0xFFFF0000u);                   \
        acc1.z += cc * __uint_as_float((u).w << 16);                           \
        acc1.w += cc * __uint_as_float((u).w & 0xFFFF0000u);                   \
    } while (0)

// -------- K5: fused sort + per-node register gather (bf16 x) + matmul ------
// Block = one bucket of 32 nodes; 256 threads = 32 node-groups x 8 lanes.
// r0 structure with ONE change: crecs chunk is register-preloaded; the
// preload of chunk c+1 is issued BEFORE the FMA phase of chunk c, so the
// sort phases (pass1/pass2) run entirely from registers with no global
// load stall, and the next chunk's loads ride under the FMA phase (T14).
__global__ __launch_bounds__(256) void gather_out_kernel(
        const unsigned* __restrict__ crecs, const int* __restrict__ bstartC,
        const int* __restrict__ totalsC, const float* __restrict__ dinv,
        const ushort* __restrict__ xh, const float* __restrict__ x,
        const float* __restrict__ W0, const float* __restrict__ W1,
        const float* __restrict__ bias, float* __restrict__ out) {
    __shared__ __align__(16) char smemA[32 * AST * 4];  // srt (8192B) | xs
    __shared__ __align__(16) char smemB[32 * AST * 4];  // ts
    __shared__ int cnt32[32];
    __shared__ int start32[32];
    __shared__ int cur32[32];
    int2*  srt = (int2*)smemA;
    float* xs  = (float*)smemA;
    float* ts  = (float*)smemB;

    int tid = threadIdx.x;
    int b   = blockIdx.x;
    int n0  = b * 32;
    int g   = tid >> 3;      // node within bucket
    int j   = tid & 7;       // lane owns features 8j..8j+7

    int base = bstartC[b];
    int cnt  = totalsC[b];

    float4 acc0 = make_float4(0.f, 0.f, 0.f, 0.f);
    float4 acc1 = make_float4(0.f, 0.f, 0.f, 0.f);
    const ushort* xhj = xh + (j << 3);

    // preload chunk 0 records into registers (<=4 per thread)
    unsigned pv[4];
    {
        int m0 = min(CAP, cnt);
        #pragma unroll
        for (int u = 0; u < 4; ++u) {
            int i = tid + u * 256;
            if (i < m0) pv[u] = crecs[base + i];
        }
    }

    for (int cb = 0; cb < cnt; cb += CAP) {
        int m = min(CAP, cnt - cb);
        if (tid < 32) cnt32[tid] = 0;
        __syncthreads();
        // pass 1: histogram by coloff, from registers (no global loads)
        #pragma unroll
        for (int u = 0; u < 4; ++u)
            if (tid + u * 256 < m) atomicAdd(&cnt32[(pv[u] >> 10) & 31u], 1);
        __syncthreads();
        if (tid < 32) {               // exclusive scan via shfl (wave 0)
            int v = cnt32[tid];
            int inc = v;
            #pragma unroll
            for (int d = 1; d < 32; d <<= 1) {
                int u = __shfl_up(inc, d, 32);
                if (tid >= d) inc += u;
            }
            start32[tid] = inc - v;
            cur32[tid]   = inc - v;
        }
        __syncthreads();
        // pass 2: decode + place, from registers (dinv + dequant folded)
        #pragma unroll
        for (int u = 0; u < 4; ++u) {
            int i = tid + u * 256;
            if (i < m) {
                unsigned uu = pv[u];
                int r = uu >> 15;
                float cf = (float)(uu & 1023u) * (1.f / 1024.f) * dinv[r];
                int p = atomicAdd(&cur32[(uu >> 10) & 31u], 1);
                srt[p] = make_int2(r, __float_as_int(cf));
            }
        }
        __syncthreads();
        // issue next chunk's record loads NOW — they land during the FMA phase
        {
            int cb2 = cb + CAP;
            if (cb2 < cnt) {
                int m2 = min(CAP, cnt - cb2);
                #pragma unroll
                for (int u = 0; u < 4; ++u) {
                    int i = tid + u * 256;
                    if (i < m2) pv[u] = crecs[base + cb2 + i];
                }
            }
        }
        // per-node accumulation from bf16 rows (1 uint4 = 8 features / edge)
        int ks = start32[g];
        int ke = cur32[g];
        int k = ks;
        for (; k + 3 < ke; k += 4) {
            int2 e0 = srt[k + 0];
            int2 e1 = srt[k + 1];
            int2 e2 = srt[k + 2];
            int2 e3 = srt[k + 3];
            uint4 u0 = *(const uint4*)(xhj + ((size_t)e0.x << 6));
            uint4 u1 = *(const uint4*)(xhj + ((size_t)e1.x << 6));
            uint4 u2 = *(const uint4*)(xhj + ((size_t)e2.x << 6));
            uint4 u3 = *(const uint4*)(xhj + ((size_t)e3.x << 6));
            FMA_BF16(e0, u0);
            FMA_BF16(e1, u1);
            FMA_BF16(e2, u2);
            FMA_BF16(e3, u3);
        }
        for (; k < ke; ++k) {
            int2 e0 = srt[k];
            uint4 u0 = *(const uint4*)(xhj + ((size_t)e0.x << 6));
            FMA_BF16(e0, u0);
        }
        __syncthreads();   // srt reads done before next chunk / xs overwrite
    }

    // Phase C: ts = -dinv[n]*acc, stage xs (fp32), matmul epilogue.
    float dn = -dinv[n0 + g];
    float* tp = ts + g * AST + (j << 3);
    *(float4*)tp       = make_float4(dn * acc0.x, dn * acc0.y, dn * acc0.z, dn * acc0.w);
    *(float4*)(tp + 4) = make_float4(dn * acc1.x, dn * acc1.y, dn * acc1.z, dn * acc1.w);
    for (int i = tid; i < 512; i += 256) {          // 512 float4 = 32x64 floats
        int nn = i >> 4;
        int kk = (i & 15) << 2;
        *(float4*)&xs[nn * AST + kk] = *(const float4*)(x + (size_t)n0 * D + i * 4);
    }
    __syncthreads();

    int jl = j << 3;
    float4 o0 = *(const float4*)(bias + jl);
    float4 o1 = *(const float4*)(bias + jl + 4);
    for (int k = 0; k < D; k += 4) {
        float4 av = *(const float4*)&xs[g * AST + k];
        float4 tv = *(const float4*)&ts[g * AST + k];
        #pragma unroll
        for (int u = 0; u < 4; ++u) {
            float a = (u == 0) ? av.x : (u == 1) ? av.y : (u == 2) ? av.z : av.w;
            float t = (u == 0) ? tv.x : (u == 1) ? tv.y : (u == 2) ? tv.z : tv.w;
            const float4 w00 = *(const float4*)(W0 + (size_t)(k + u) * D + jl);
            const float4 w01 = *(const float4*)(W0 + (size_t)(k + u) * D + jl + 4);
            const float4 w10 = *(const float4*)(W1 + (size_t)(k + u) * D + jl);
            const float4 w11 = *(const float4*)(W1 + (size_t)(k + u) * D + jl + 4);
            o0.x += a * w00.x + t * w10.x;
            o0.y += a * w00.y + t * w10.y;
            o0.z += a * w00.z + t * w10.z;
            o0.w += a * w00.w + t * w10.w;
            o1.x += a * w01.x + t * w11.x;
            o1.y += a * w01.y + t * w11.y;
            o1.z += a * w01.z + t * w11.z;
            o1.w += a * w01.w + t * w11.w;
        }
    }
    float* op = out + (size_t)(n0 + g) * D + jl;
    *(float4*)op       = o0;
    *(float4*)(op + 4) = o1;
}

extern "C" void kernel_launch(void* const* d_in, const int* in_sizes, int n_in,
                              void* d_out, int out_size, void* d_ws, size_t ws_size,
                              hipStream_t stream) {
    const float* x    = (const float*)d_in[0];
    const int*   eidx = (const int*)d_in[1];   // [2, E]: row then col
    const float* ew   = (const float*)d_in[2];
    const float* W0   = (const float*)d_in[3];
    const float* W1   = (const float*)d_in[4];
    const float* b    = (const float*)d_in[5];
    float* out = (float*)d_out;

    const int* row = eidx;
    const int* col = eidx + N_EDGES;

    // Workspace layout (4B words), fully overwritten each call, no memset.
    // crecs 6.4MB + rrecs 6.4MB + mats 3.2MB + small + dinv 0.4MB + xh 12.8MB
    // ~= 29.3 MB total. (r0-identical)
    unsigned* crecs   = (unsigned*)d_ws;                               // E
    unsigned* rrecs   = crecs + N_EDGES;                               // E
    int*      matC    = (int*)(rrecs + N_EDGES);                       // NB*NBUCK_PAD
    int*      matR    = matC + (size_t)NB * NBUCK_PAD;                 // NB*NBUCK_PAD
    int*      totalsC = matR + (size_t)NB * NBUCK_PAD;                 // NBUCK_PAD
    int*      bstartC = totalsC + NBUCK_PAD;                           // NBUCK_PAD
    int*      totalsR = bstartC + NBUCK_PAD;                           // NBUCK_PAD
    int*      bstartR = totalsR + NBUCK_PAD;                           // NBUCK_PAD
    float*    dinv    = (float*)(bstartR + NBUCK_PAD);                 // N
    ushort*   xh      = (ushort*)(dinv + N_NODES);                     // N*D ushort

    tobf16_kernel    <<<N_NODES * D / (256 * 8), 256, 0, stream>>>(x, xh);
    count_kernel     <<<NB, 512, 0, stream>>>(row, col, matC, matR);
    blockscan_kernel <<<2 * NGRP, 256, 0, stream>>>(matC, matR, totalsC, totalsR);
    totscan_kernel   <<<2, 256, 0, stream>>>(totalsC, bstartC, totalsR, bstartR);
    scatter_kernel   <<<NB, 512, 0, stream>>>(row, col, ew, matC, matR,
                                              bstartC, bstartR, crecs, rrecs);
    deg_kernel       <<<NBUCK, 256, 0, stream>>>(rrecs, bstartR, totalsR, dinv);
    gather_out_kernel<<<NBUCK, 256, 0, stream>>>(crecs, bstartC, totalsC, dinv,
                                                 xh, x, W0, W1, b, out);
}